// Round 1
// baseline (445.117 us; speedup 1.0000x reference)
//
#include <hip/hip_runtime.h>

// Forward-fill (LOCF) along L for x:(B,L,N) fp32, NaN = missing.
// Outputs: x_filled (B*L*N fp32) then mask as 0.0/1.0 fp32, concatenated.
//
// Three-phase chunked scan (R5: replaced k_fill's O(chunk) carry loop):
//   k_tail : per (b, chunk, n) last observed value in chunk (NaN if none) -> tail.
//            x read with REGULAR loads (warms L3; x = 134 MB < 256 MiB L3).
//   k_scan : exclusive LOCF-prefix of tails along chunks -> carry array.
//            One wave per b, lanes = n4. Tiny (4-16 MiB, L2-resident).
//   k_fill : carry-in is ONE load (was: up to C-1 latency-exposed L2 loads,
//            imbalanced across waves). LC dropped 32->16 so the grid doubles
//            (2048 blocks, 32 waves/CU) for latency hiding on the fill loop.
//            out/mask stores are nontemporal (pure streaming, no reuse).
//
// R3 lesson: nt loads on x prevented L3 allocation -> k_fill re-read x from
// HBM (+40 us). nt belongs on the store streams only.
// R2 lesson: __builtin_nontemporal_* requires clang ext_vector_type.

typedef float floatx4 __attribute__((ext_vector_type(4)));

constexpr int B = 32, L = 4096, N = 256;
constexpr int N4 = N / 4;   // float4 lanes across channels (64 == one wave)
constexpr int CPB = 4;      // chunks per 256-thread block (one wave per chunk)

__device__ __forceinline__ float dev_nan() { return __int_as_float(0x7fc00000); }

// last[c] = v[c] if v[c] is observed (non-NaN) else last[c]
__device__ __forceinline__ void upd(floatx4& last, const floatx4 v) {
    last.x = (v.x == v.x) ? v.x : last.x;
    last.y = (v.y == v.y) ? v.y : last.y;
    last.z = (v.z == v.z) ? v.z : last.z;
    last.w = (v.w == v.w) ? v.w : last.w;
}

__device__ __forceinline__ floatx4 nan4() {
    return floatx4{dev_nan(), dev_nan(), dev_nan(), dev_nan()};
}

template <int LC>
__global__ __launch_bounds__(256) void k_tail(const floatx4* __restrict__ x4,
                                              floatx4* __restrict__ tail4) {
    constexpr int C = L / LC;
    const int gid   = blockIdx.x;
    const int b     = gid / (C / CPB);
    const int chunk = (gid % (C / CPB)) * CPB + (threadIdx.x >> 6);
    const int n4    = threadIdx.x & 63;

    const floatx4* p = x4 + (long)(b * L + chunk * LC) * N4 + n4;
    floatx4 last = nan4();
#pragma unroll 8
    for (int i = 0; i < LC; ++i) {
        floatx4 v = p[(long)i * N4];   // caching load: warm L3 for k_fill
        upd(last, v);
    }
    tail4[(long)(b * C + chunk) * N4 + n4] = last;
}

// Exclusive LOCF-prefix over chunk tails: carry[b,c] = combine(tail[b,0..c-1]).
// Distinct restrict in/out arrays so the compiler can hoist loads past stores
// (in-place aliasing would serialize the unrolled loop).
template <int LC>
__global__ __launch_bounds__(64) void k_scan(const floatx4* __restrict__ tail4,
                                             floatx4* __restrict__ carry4) {
    constexpr int C = L / LC;
    const int b  = blockIdx.x;      // grid = B
    const int n4 = threadIdx.x;     // one wave, lanes = n4
    const floatx4* t = tail4  + (long)b * C * N4 + n4;
    floatx4*       c = carry4 + (long)b * C * N4 + n4;
    floatx4 carry = nan4();
#pragma unroll 8
    for (int j = 0; j < C; ++j) {
        floatx4 tj = t[(long)j * N4];
        c[(long)j * N4] = carry;
        upd(carry, tj);
    }
}

// SCANNED: t4 = exclusive carries (one load). !SCANNED: t4 = raw tails
// (legacy O(chunk) loop, 4-way pipelined) for small-workspace fallback.
template <int LC, bool SCANNED>
__global__ __launch_bounds__(256) void k_fill(const floatx4* __restrict__ x4,
                                              const floatx4* __restrict__ t4,
                                              floatx4* __restrict__ out4,
                                              floatx4* __restrict__ m4) {
    constexpr int C = L / LC;
    const int gid   = blockIdx.x;
    const int b     = gid / (C / CPB);
    const int chunk = (gid % (C / CPB)) * CPB + (threadIdx.x >> 6);
    const int n4    = threadIdx.x & 63;

    floatx4 last;
    if constexpr (SCANNED) {
        last = t4[(long)(b * C + chunk) * N4 + n4];
    } else {
        // Legacy carry: combine tails of preceding chunks, 4 independent
        // accumulators to keep >=4 L2 loads in flight.
        floatx4 l0 = nan4(), l1 = nan4(), l2 = nan4(), l3 = nan4();
        const floatx4* tb = t4 + (long)b * C * N4 + n4;
        int j = 0;
        for (; j + 4 <= chunk; j += 4) {
            floatx4 a0 = tb[(long)(j + 0) * N4];
            floatx4 a1 = tb[(long)(j + 1) * N4];
            floatx4 a2 = tb[(long)(j + 2) * N4];
            floatx4 a3 = tb[(long)(j + 3) * N4];
            upd(l0, a0); upd(l1, a1); upd(l2, a2); upd(l3, a3);
        }
        for (; j < chunk; ++j) upd(l0, tb[(long)j * N4]);
        // merge in chunk order: l0 holds oldest stream, later streams win
        last = l0; upd(last, l1); upd(last, l2); upd(last, l3);
        // NOTE: interleaved accumulators preserve order because within each
        // residue class j%4 order is kept, and across classes the final merge
        // is wrong only if two classes observed the same channel... it isn't:
        // see correction below -- we instead merge by re-walking remainder.
    }

    const long base = (long)(b * L + chunk * LC) * N4 + n4;
#pragma unroll 4
    for (int i = 0; i < LC; ++i) {
        const long idx = base + (long)i * N4;
        floatx4 v = x4[idx];           // caching load: should hit L3
        const bool ox = (v.x == v.x);
        const bool oy = (v.y == v.y);
        const bool oz = (v.z == v.z);
        const bool ow = (v.w == v.w);
        upd(last, v);
        floatx4 o;
        o.x = (last.x == last.x) ? last.x : 0.0f;
        o.y = (last.y == last.y) ? last.y : 0.0f;
        o.z = (last.z == last.z) ? last.z : 0.0f;
        o.w = (last.w == last.w) ? last.w : 0.0f;
        __builtin_nontemporal_store(o, out4 + idx);
        if (m4) {
            floatx4 m = {ox ? 1.0f : 0.0f, oy ? 1.0f : 0.0f,
                         oz ? 1.0f : 0.0f, ow ? 1.0f : 0.0f};
            __builtin_nontemporal_store(m, m4 + idx);
        }
    }
}

template <int LC, bool SCANNED>
static void run_all(const float* x, float* out, float* mask_out, void* d_ws,
                    hipStream_t stream) {
    constexpr int C = L / LC;
    float* tail  = (float*)d_ws;
    if constexpr (SCANNED) {
        float* carry = tail + (long)B * C * N;
        k_tail<LC><<<B * C / CPB, 256, 0, stream>>>((const floatx4*)x,
                                                    (floatx4*)tail);
        k_scan<LC><<<B, 64, 0, stream>>>((const floatx4*)tail, (floatx4*)carry);
        k_fill<LC, true><<<B * C / CPB, 256, 0, stream>>>((const floatx4*)x,
                                                          (const floatx4*)carry,
                                                          (floatx4*)out,
                                                          (floatx4*)mask_out);
    } else {
        k_tail<LC><<<B * C / CPB, 256, 0, stream>>>((const floatx4*)x,
                                                    (floatx4*)tail);
        k_fill<LC, false><<<B * C / CPB, 256, 0, stream>>>((const floatx4*)x,
                                                           (const floatx4*)tail,
                                                           (floatx4*)out,
                                                           (floatx4*)mask_out);
    }
}

extern "C" void kernel_launch(void* const* d_in, const int* in_sizes, int n_in,
                              void* d_out, int out_size, void* d_ws, size_t ws_size,
                              hipStream_t stream) {
    const float* x = (const float*)d_in[0];
    const long n_total = (long)B * L * N;  // 33,554,432

    float* out = (float*)d_out;
    float* mask_out = ((long)out_size >= 2 * n_total) ? out + n_total : nullptr;

    auto bytes = [](int C) { return (size_t)B * C * N * sizeof(float); };

    if (ws_size >= 2 * bytes(L / 16)) {
        // LC=16 (C=256): 2x8 MiB scratch, 2048-block grids, 32 waves/CU.
        run_all<16, true>(x, out, mask_out, d_ws, stream);
    } else if (ws_size >= 2 * bytes(L / 32)) {
        // LC=32 (C=128): 2x4 MiB scratch.
        run_all<32, true>(x, out, mask_out, d_ws, stream);
    } else if (ws_size >= 2 * bytes(L / 128)) {
        // LC=128 (C=32): 2x1 MiB scratch.
        run_all<128, true>(x, out, mask_out, d_ws, stream);
    } else if (ws_size >= bytes(L / 32)) {
        // Legacy 2-kernel path, 4 MiB.
        run_all<32, false>(x, out, mask_out, d_ws, stream);
    } else {
        // Legacy 2-kernel path, 1 MiB.
        run_all<128, false>(x, out, mask_out, d_ws, stream);
    }
}

// Round 2
// 428.092 us; speedup vs baseline: 1.0398x; 1.0398x over previous
//
#include <hip/hip_runtime.h>

// Forward-fill (LOCF) along L for x:(B,L,N) fp32, NaN = missing.
// Outputs: x_filled (B*L*N fp32) then mask as 0.0/1.0 fp32, concatenated.
//
// Three-phase chunked scan:
//   k_tail : per (b, chunk, n) last observed value in chunk (NaN if none) -> tail.
//   k_scan : exclusive LOCF-prefix of tails along chunks -> carry array.
//   k_fill : carry-in is ONE load; fill + write out/mask (nontemporal stores).
//
// R6 (this round): REGISTER-STAGE the whole chunk. Previous version's
// "#pragma unroll 4" + serial upd chain capped in-flight loads at 4x16B=64B
// per wave (2 KB/CU at 32 waves/CU) -> Little's law gives ~1.4 TB/s, matching
// the measured ~1.24 TB/s effective. Now all LC independent loads issue
// back-to-back before any consumption: 256 B/wave in flight, ~5 KB/CU at
// ~20 waves/CU (VGPR ~90) -> target 3.5-4.5 TB/s on the streaming phases.
// R5 lesson: carry-loop removal was NEUTRAL (436.8 -> 445.1 us) -> streaming
// phases dominate; harness fillBuffer hits 6.4 TB/s so chip isn't the limit.
// R3 lesson: nt loads on x prevented L3 allocation -> k_fill re-read x from
// HBM (+40 us). nt belongs on the store streams only.
// R2 lesson: __builtin_nontemporal_* requires clang ext_vector_type.

typedef float floatx4 __attribute__((ext_vector_type(4)));

constexpr int B = 32, L = 4096, N = 256;
constexpr int N4 = N / 4;   // float4 lanes across channels (64 == one wave)
constexpr int CPB = 4;      // chunks per 256-thread block (one wave per chunk)

__device__ __forceinline__ float dev_nan() { return __int_as_float(0x7fc00000); }

__device__ __forceinline__ floatx4 nan4() {
    return floatx4{dev_nan(), dev_nan(), dev_nan(), dev_nan()};
}

// last[c] = v[c] if v[c] is observed (non-NaN) else last[c]
__device__ __forceinline__ void upd(floatx4& last, const floatx4 v) {
    last.x = (v.x == v.x) ? v.x : last.x;
    last.y = (v.y == v.y) ? v.y : last.y;
    last.z = (v.z == v.z) ? v.z : last.z;
    last.w = (v.w == v.w) ? v.w : last.w;
}

template <int LC>
__global__ __launch_bounds__(256) void k_tail(const floatx4* __restrict__ x4,
                                              floatx4* __restrict__ tail4) {
    constexpr int C = L / LC;
    const int gid   = blockIdx.x;
    const int b     = gid / (C / CPB);
    const int chunk = (gid % (C / CPB)) * CPB + (threadIdx.x >> 6);
    const int n4    = threadIdx.x & 63;

    const floatx4* p = x4 + (long)(b * L + chunk * LC) * N4 + n4;
    // Issue ALL LC loads before consuming any (max memory-level parallelism).
    floatx4 v[LC];
#pragma unroll
    for (int i = 0; i < LC; ++i) v[i] = p[(long)i * N4];
    floatx4 last = nan4();
#pragma unroll
    for (int i = 0; i < LC; ++i) upd(last, v[i]);
    tail4[(long)(b * C + chunk) * N4 + n4] = last;
}

// Exclusive LOCF-prefix over chunk tails: carry[b,c] = combine(tail[b,0..c-1]).
// Grouped register staging (16 tails per batch) so the serial carry chain
// overlaps a full batch of loads instead of one load at a time.
template <int LC>
__global__ __launch_bounds__(64) void k_scan(const floatx4* __restrict__ tail4,
                                             floatx4* __restrict__ carry4) {
    constexpr int C = L / LC;
    constexpr int G = 16;          // C is 256/128/32 -> all divisible by 16
    const int b  = blockIdx.x;     // grid = B
    const int n4 = threadIdx.x;    // one wave, lanes = n4
    const floatx4* t = tail4  + (long)b * C * N4 + n4;
    floatx4*       c = carry4 + (long)b * C * N4 + n4;
    floatx4 carry = nan4();
    for (int g = 0; g < C; g += G) {
        floatx4 tv[G];
#pragma unroll
        for (int j = 0; j < G; ++j) tv[j] = t[(long)(g + j) * N4];
#pragma unroll
        for (int j = 0; j < G; ++j) {
            c[(long)(g + j) * N4] = carry;   // exclusive: store BEFORE combine
            upd(carry, tv[j]);
        }
    }
}

// SCANNED: t4 = exclusive carries (one load). !SCANNED: t4 = raw tails
// (legacy serial carry loop) for small-workspace fallback.
template <int LC, bool SCANNED>
__global__ __launch_bounds__(256) void k_fill(const floatx4* __restrict__ x4,
                                              const floatx4* __restrict__ t4,
                                              floatx4* __restrict__ out4,
                                              floatx4* __restrict__ m4) {
    constexpr int C = L / LC;
    const int gid   = blockIdx.x;
    const int b     = gid / (C / CPB);
    const int chunk = (gid % (C / CPB)) * CPB + (threadIdx.x >> 6);
    const int n4    = threadIdx.x & 63;

    // Carry-in load first so it overlaps the chunk loads below.
    floatx4 last;
    if constexpr (SCANNED) {
        last = t4[(long)(b * C + chunk) * N4 + n4];
    } else {
        floatx4 l = nan4();
        const floatx4* tb = t4 + (long)b * C * N4 + n4;
        for (int j = 0; j < chunk; ++j) upd(l, tb[(long)j * N4]);
        last = l;
    }

    const long base = (long)(b * L + chunk * LC) * N4 + n4;
    // Issue ALL LC chunk loads back-to-back (register staging, max MLP).
    floatx4 v[LC];
#pragma unroll
    for (int i = 0; i < LC; ++i) v[i] = x4[base + (long)i * N4];

#pragma unroll
    for (int i = 0; i < LC; ++i) {
        const long idx = base + (long)i * N4;
        const floatx4 val = v[i];
        const bool ox = (val.x == val.x);
        const bool oy = (val.y == val.y);
        const bool oz = (val.z == val.z);
        const bool ow = (val.w == val.w);
        upd(last, val);
        floatx4 o;
        o.x = (last.x == last.x) ? last.x : 0.0f;
        o.y = (last.y == last.y) ? last.y : 0.0f;
        o.z = (last.z == last.z) ? last.z : 0.0f;
        o.w = (last.w == last.w) ? last.w : 0.0f;
        __builtin_nontemporal_store(o, out4 + idx);
        if (m4) {
            floatx4 m = {ox ? 1.0f : 0.0f, oy ? 1.0f : 0.0f,
                         oz ? 1.0f : 0.0f, ow ? 1.0f : 0.0f};
            __builtin_nontemporal_store(m, m4 + idx);
        }
    }
}

template <int LC, bool SCANNED>
static void run_all(const float* x, float* out, float* mask_out, void* d_ws,
                    hipStream_t stream) {
    constexpr int C = L / LC;
    float* tail  = (float*)d_ws;
    if constexpr (SCANNED) {
        float* carry = tail + (long)B * C * N;
        k_tail<LC><<<B * C / CPB, 256, 0, stream>>>((const floatx4*)x,
                                                    (floatx4*)tail);
        k_scan<LC><<<B, 64, 0, stream>>>((const floatx4*)tail, (floatx4*)carry);
        k_fill<LC, true><<<B * C / CPB, 256, 0, stream>>>((const floatx4*)x,
                                                          (const floatx4*)carry,
                                                          (floatx4*)out,
                                                          (floatx4*)mask_out);
    } else {
        k_tail<LC><<<B * C / CPB, 256, 0, stream>>>((const floatx4*)x,
                                                    (floatx4*)tail);
        k_fill<LC, false><<<B * C / CPB, 256, 0, stream>>>((const floatx4*)x,
                                                           (const floatx4*)tail,
                                                           (floatx4*)out,
                                                           (floatx4*)mask_out);
    }
}

extern "C" void kernel_launch(void* const* d_in, const int* in_sizes, int n_in,
                              void* d_out, int out_size, void* d_ws, size_t ws_size,
                              hipStream_t stream) {
    const float* x = (const float*)d_in[0];
    const long n_total = (long)B * L * N;  // 33,554,432

    float* out = (float*)d_out;
    float* mask_out = ((long)out_size >= 2 * n_total) ? out + n_total : nullptr;

    auto bytes = [](int C) { return (size_t)B * C * N * sizeof(float); };

    if (ws_size >= 2 * bytes(L / 16)) {
        // LC=16 (C=256): 2x8 MiB scratch, 2048-block grids, 16 loads in
        // flight per wave (256 B), ~20 waves/CU at VGPR~90 -> ~5 KB/CU MLP.
        run_all<16, true>(x, out, mask_out, d_ws, stream);
    } else if (ws_size >= 2 * bytes(L / 32)) {
        // LC=32 (C=128): 2x4 MiB scratch.
        run_all<32, true>(x, out, mask_out, d_ws, stream);
    } else if (ws_size >= 2 * bytes(L / 128)) {
        // LC=128 (C=32): 2x1 MiB scratch.
        run_all<128, true>(x, out, mask_out, d_ws, stream);
    } else if (ws_size >= bytes(L / 32)) {
        // Legacy 2-kernel path, 4 MiB.
        run_all<32, false>(x, out, mask_out, d_ws, stream);
    } else {
        // Legacy 2-kernel path, 1 MiB.
        run_all<128, false>(x, out, mask_out, d_ws, stream);
    }
}